// Round 7
// baseline (657.818 us; speedup 1.0000x reference)
//
#include <hip/hip_runtime.h>
#include <hip/hip_bf16.h>
#include <stdint.h>

typedef __bf16 bf16_t;
typedef __bf16 bf16x8 __attribute__((ext_vector_type(8)));
typedef float f32x4 __attribute__((ext_vector_type(4)));

#define LOG2E 1.44269504088896340736f
#define LN2 0.69314718055994530942f

__device__ __forceinline__ float fast_exp2(float x) { return __builtin_amdgcn_exp2f(x); }
__device__ __forceinline__ float fast_log2(float x) { return __builtin_amdgcn_logf(x); }
__device__ __forceinline__ float fast_rcp(float x) { return __builtin_amdgcn_rcpf(x); }

// arg pre-scaled by LOG2E: softplus(x), t = x*LOG2E
__device__ __forceinline__ float softplus_t(float t) {
    float sp = LN2 * fast_log2(1.0f + fast_exp2(t));
    return (t > 28.9f) ? t * LN2 : sp;
}
// arg pre-scaled by 2*LOG2E: tanh(x), t = 2x*LOG2E
__device__ __forceinline__ float tanh_t(float t) {
    float e = fast_exp2(t);
    return 1.0f - 2.0f * fast_rcp(1.0f + e);
}

// f32 -> bf16 (RNE), result in low 16 bits
__device__ __forceinline__ uint32_t cvt_bf16(float a) {
    uint32_t r;
    asm("v_cvt_pk_bf16_f32 %0, %1, %2" : "=v"(r) : "v"(a), "v"(a));
    return r;
}
__device__ __forceinline__ void store_hl(float v, uint16_t* ph, uint16_t* pl) {
    uint32_t h = cvt_bf16(v);
    float hf = __builtin_bit_cast(float, h << 16);
    uint32_t lo = cvt_bf16(v - hf);
    *ph = (uint16_t)h;
    *pl = (uint16_t)lo;
}

// lane l <-> l^16 exchange (LDS swizzle, no LDS storage touched)
__device__ __forceinline__ float swz16(float v) {
    int r = __builtin_amdgcn_ds_swizzle(__builtin_bit_cast(int, v), 0x401F);
    return __builtin_bit_cast(float, r);
}

// B=4096, L=64, C=7, H=32, K=2 -> 504 RK4 stages, h=0.5
// 1024 blocks x 64 threads: ONE WAVE owns 4 batch rows, everything register-
// resident (W2 in 128 VGPRs), LDS only as same-wave mailbox. NO BARRIERS.
// GEMV1: A=z(rows=batch, dup mod4), B=W1^T -> d1; h1 select is 6 cndmasks.
// GEMV2 (transposed): A=W2p(rows=n=8h+c), B=h1^T(cols=batch dup mod4);
// c-contraction in-lane (3 adds) + xor16 swizzle partner add.
__global__ __launch_bounds__(64, 1) void cde_kernel(
    const float* __restrict__ x,    // (4096,64,7)
    const float* __restrict__ Wi,   // (32,7)
    const float* __restrict__ bi,   // (32,)
    const float* __restrict__ W1,   // (32,32)
    const float* __restrict__ b1,   // (32,)
    const float* __restrict__ W2,   // (224,32)
    const float* __restrict__ b2,   // (224,)
    const float* __restrict__ Wo1,  // (16,32)
    const float* __restrict__ bo1,  // (16,)
    const float* __restrict__ Wo2,  // (3,16)
    const float* __restrict__ bo2,  // (3,)
    float* __restrict__ out)        // (4096,3)
{
    __shared__ float diffs[4][441];     // [b][i*7+c]
    __shared__ float dxL[4][8];         // [b][c], col 7 = 0
    __shared__ float b2L[32][8];        // [h][c] pre-scaled bias, col 7 = 0
    __shared__ uint16_t zhS[4][32], zlS[4][32];    // z hi/lo bf16 bits [b][h]
    __shared__ uint16_t h1hS[4][32], h1lS[4][32];  // h1 hi/lo [b][i]
    __shared__ float zfin[4][32];
    __shared__ float ubuf[4][16];

    const int l = threadIdx.x;       // 0..63
    const int r0 = blockIdx.x * 4;

    const int ar = l & 15;           // MFMA row(A)/col(B)/col(D)
    const int chunk = l >> 4;        // k-chunk 0..3 (== quarter Q)
    const int b3 = l & 3;            // batch row this lane serves (dup'd cols)
    const int kq = (l >> 2) & 3;     // tile-in-pass this lane's D-copy holds
    const int qlo = chunk & 1;       // c-half selector
    const int qhi = chunk >> 1;      // h LSB contribution

    // duty: lane owns z[b3][h0] and z[b3][h0+8]
    const int h0 = 16 * qlo + 2 * kq + qhi;
    const int h1d = h0 + 8;

    // ---------- weight preload (pre-scaled, hi/lo bf16 split) ----------
    bf16x8 w1h[2], w1l[2];
    float b1c[2];
#pragma unroll
    for (int T = 0; T < 2; ++T) {
        const float* p = &W1[(16 * T + ar) * 32 + 8 * chunk];
#pragma unroll
        for (int j = 0; j < 8; ++j) {
            float v = p[j] * LOG2E;
            bf16_t hh = (bf16_t)v;
            w1h[T][j] = hh;
            w1l[T][j] = (bf16_t)(v - (float)hh);
        }
        b1c[T] = b1[16 * T + ar] * LOG2E;
    }

    bf16x8 w2h[16], w2l[16];        // A-frags: W2p[16T+ar][8chunk+j]
    {
        const int hh_ = ar >> 3, cc = ar & 7;
#pragma unroll
        for (int T = 0; T < 16; ++T) {
            int h = 2 * T + hh_;
            if (cc < 7) {
                const float* p = &W2[(h * 7 + cc) * 32 + 8 * chunk];
#pragma unroll
                for (int j = 0; j < 8; ++j) {
                    float v = p[j] * (2.0f * LOG2E);
                    bf16_t hv = (bf16_t)v;
                    w2h[T][j] = hv;
                    w2l[T][j] = (bf16_t)(v - (float)hv);
                }
            } else {
#pragma unroll
                for (int j = 0; j < 8; ++j) { w2h[T][j] = (bf16_t)0.0f; w2l[T][j] = (bf16_t)0.0f; }
            }
        }
    }

    // ---------- LDS tables (single wave: no barrier needed, ever) ----------
    for (int e = l; e < 256; e += 64) {
        int h = e >> 3, c = e & 7;
        b2L[h][c] = (c < 7) ? b2[h * 7 + c] * (2.0f * LOG2E) : 0.0f;
    }
    for (int e = l; e < 4 * 441; e += 64) {
        int r = e / 441, rem = e - r * 441;
        const float* px = &x[(size_t)(r0 + r) * 448];
        diffs[r][rem] = px[rem + 7] - px[rem];
    }
    if (l < 4) dxL[l][7] = 0.0f;

    // ---------- z0 at duty positions ----------
    float zb0, zb1, ka0 = 0.0f, ka1 = 0.0f;
    {
        const float* px = &x[(size_t)(r0 + b3) * 448];
        float a0 = bi[h0], a1 = bi[h1d];
#pragma unroll
        for (int c = 0; c < 7; ++c) {
            a0 += px[c] * Wi[h0 * 7 + c];
            a1 += px[c] * Wi[h1d * 7 + c];
        }
        zb0 = a0; zb1 = a1;
        store_hl(zb0, &zhS[b3][h0], &zlS[b3][h0]);
        store_hl(zb1, &zhS[b3][h1d], &zlS[b3][h1d]);
    }

    // hoisted pointers
    const bf16x8* pZh = (const bf16x8*)&zhS[b3][8 * chunk];
    const bf16x8* pZl = (const bf16x8*)&zlS[b3][8 * chunk];
    const bf16x8* pHh = (const bf16x8*)&h1hS[b3][8 * chunk];
    const bf16x8* pHl = (const bf16x8*)&h1lS[b3][8 * chunk];
    const f32x4* pDx = (const f32x4*)&dxL[b3][4 * qlo];
    const char* pB2 = (const char*)&b2L[2 * kq + qhi][4 * qlo];
    const int bQ = chunk & 1;               // h1 duty b (X0)
    const int ihQ = 16 * (chunk >> 1) + ar; // h1 duty i
    uint16_t* pH0h = &h1hS[bQ][ihQ];
    uint16_t* pH0l = &h1lS[bQ][ihQ];
    uint16_t* pH1h = &h1hS[bQ + 2][ihQ];
    uint16_t* pH1l = &h1lS[bQ + 2][ihQ];
    uint16_t* pZ0h = &zhS[b3][h0];
    uint16_t* pZ0l = &zlS[b3][h0];
    uint16_t* pZ1h = &zhS[b3][h1d];
    uint16_t* pZ1l = &zlS[b3][h1d];
    const int bdx = l / 7, cdx = l - 7 * (l / 7);   // dx duty (l<28)
    const bool dxact = l < 28;
    const bool qodd = (chunk & 1) != 0;

    for (int it = 0; it < 504; ++it) {
        const int s = it & 3;
        const int kk = it >> 2;

        // ---- GEMV1: d1[T] = z @ W1p^T (+b1), batch rows dup'd mod 4 ----
        bf16x8 azh = *pZh;
        bf16x8 azl = *pZl;
        f32x4 d1[2];
#pragma unroll
        for (int T = 0; T < 2; ++T) {
            f32x4 c0 = {b1c[T], b1c[T], b1c[T], b1c[T]};
            f32x4 m1 = __builtin_amdgcn_mfma_f32_16x16x32_bf16(azh, w1h[T], c0, 0, 0, 0);
            f32x4 m2 = __builtin_amdgcn_mfma_f32_16x16x32_bf16(azl, w1h[T], m1, 0, 0, 0);
            d1[T]    = __builtin_amdgcn_mfma_f32_16x16x32_bf16(azh, w1l[T], m2, 0, 0, 0);
        }
        // select this lane's two h1 duties from the duplicated D tiles:
        // X0 -> (b = chunk&1, i = ihQ), X1 -> (b = 2+(chunk&1), i = ihQ)
        {
            float e0 = qodd ? d1[0][1] : d1[0][0];
            float e1 = qodd ? d1[1][1] : d1[1][0];
            float X0 = (chunk >> 1) ? e1 : e0;
            float f0 = qodd ? d1[0][3] : d1[0][2];
            float f1 = qodd ? d1[1][3] : d1[1][2];
            float X1 = (chunk >> 1) ? f1 : f0;
            store_hl(softplus_t(X0), pH0h, pH0l);
            store_hl(softplus_t(X1), pH1h, pH1l);
        }

        // ---- dx for this stage (fills the h1 write->read gap) ----
        if (s != 2 && dxact) {
            int m = 2 * kk + (s == 0 ? 0 : (s == 3 ? 2 : 1));   // t = 0.25*m
            int i = m >> 2; if (i > 62) i = 62;
            float f = 0.25f * (float)(m - 4 * i);
            float D = diffs[bdx][i * 7 + cdx];
            float a = diffs[bdx][(i > 0 ? i - 1 : 0) * 7 + cdx];
            dxL[bdx][cdx] = a + (D - a) * (f * (4.0f - 3.0f * f));
        }

        // ---- GEMV2 (transposed): D[n, b] over 16 tiles, 4 passes ----
        bf16x8 ahh = *pHh;
        bf16x8 ahl = *pHl;
        f32x4 dxv = *pDx;
        float kd0 = 0.0f, kd1 = 0.0f;
#pragma unroll
        for (int p = 0; p < 4; ++p) {
            f32x4 d2[4];
#pragma unroll
            for (int t = 0; t < 4; ++t) {
                const int T = 4 * p + t;
                f32x4 zr = {0.0f, 0.0f, 0.0f, 0.0f};
                f32x4 m1 = __builtin_amdgcn_mfma_f32_16x16x32_bf16(w2h[T], ahh, zr, 0, 0, 0);
                f32x4 m2 = __builtin_amdgcn_mfma_f32_16x16x32_bf16(w2h[T], ahl, m1, 0, 0, 0);
                d2[t]    = __builtin_amdgcn_mfma_f32_16x16x32_bf16(w2l[T], ahh, m2, 0, 0, 0);
            }
            // free compaction: lane keeps tile kq's copy (cols dup'd mod 4)
            const bool kb0 = (kq & 1) != 0;
            const bool kb1 = (kq & 2) != 0;
            f32x4 bv = *(const f32x4*)(pB2 + p * 256);
            float pk = 0.0f;
#pragma unroll
            for (int r = 0; r < 4; ++r) {
                float e = kb0 ? d2[1][r] : d2[0][r];
                float o = kb0 ? d2[3][r] : d2[2][r];
                float y = kb1 ? o : e;
                pk += tanh_t(y + bv[r]) * dxv[r];
            }
            float ks = pk + swz16(pk);    // add partner c-half (lane^16)
            // duty capture: q even -> passes 0,1 ; q odd -> passes 2,3
            if (p == 0)      kd0 = qodd ? kd0 : ks;
            else if (p == 1) kd1 = qodd ? kd1 : ks;
            else if (p == 2) kd0 = qodd ? ks : kd0;
            else             kd1 = qodd ? ks : kd1;
        }

        // ---- RK4 update (uniform s) + z write-back ----
        float zs0, zs1;
        if (s == 0)      { ka0 = kd0; ka1 = kd1; zs0 = zb0 + 0.25f * kd0; zs1 = zb1 + 0.25f * kd1; }
        else if (s == 1) { ka0 += 2.0f * kd0; ka1 += 2.0f * kd1; zs0 = zb0 + 0.25f * kd0; zs1 = zb1 + 0.25f * kd1; }
        else if (s == 2) { ka0 += 2.0f * kd0; ka1 += 2.0f * kd1; zs0 = zb0 + 0.5f * kd0; zs1 = zb1 + 0.5f * kd1; }
        else             { zb0 += (1.0f / 12.0f) * (ka0 + kd0); zb1 += (1.0f / 12.0f) * (ka1 + kd1); zs0 = zb0; zs1 = zb1; }
        store_hl(zs0, pZ0h, pZ0l);
        store_hl(zs1, pZ1h, pZ1l);
    }

    // ---------- epilogue ----------
    zfin[b3][h0] = zb0;
    zfin[b3][h1d] = zb1;
    {
        int bh = l >> 4, jj = l & 15;
        float acc = bo1[jj];
#pragma unroll
        for (int h = 0; h < 32; ++h) acc += zfin[bh][h] * Wo1[jj * 32 + h];
        ubuf[bh][jj] = softplus_t(acc * LOG2E);
    }
    if (l < 12) {
        int b = l / 3, o = l - 3 * (l / 3);
        float acc = bo2[o];
#pragma unroll
        for (int j = 0; j < 16; ++j) acc += ubuf[b][j] * Wo2[o * 16 + j];
        out[(size_t)(r0 + b) * 3 + o] = acc;
    }
}

extern "C" void kernel_launch(void* const* d_in, const int* in_sizes, int n_in,
                              void* d_out, int out_size, void* d_ws, size_t ws_size,
                              hipStream_t stream) {
    (void)in_sizes; (void)n_in; (void)d_ws; (void)ws_size; (void)out_size;
    const float* x   = (const float*)d_in[0];
    const float* Wi  = (const float*)d_in[1];
    const float* bi  = (const float*)d_in[2];
    const float* W1  = (const float*)d_in[3];
    const float* b1  = (const float*)d_in[4];
    const float* W2  = (const float*)d_in[5];
    const float* b2  = (const float*)d_in[6];
    const float* Wo1 = (const float*)d_in[7];
    const float* bo1 = (const float*)d_in[8];
    const float* Wo2 = (const float*)d_in[9];
    const float* bo2 = (const float*)d_in[10];
    cde_kernel<<<dim3(1024), dim3(64), 0, stream>>>(x, Wi, bi, W1, b1, W2, b2,
                                                    Wo1, bo1, Wo2, bo2, (float*)d_out);
}

// Round 8
// 446.040 us; speedup vs baseline: 1.4748x; 1.4748x over previous
//
#include <hip/hip_runtime.h>
#include <hip/hip_bf16.h>
#include <stdint.h>

typedef __bf16 bf16_t;
typedef __bf16 bf16x8 __attribute__((ext_vector_type(8)));
typedef float f32x4 __attribute__((ext_vector_type(4)));

#define LOG2E 1.44269504088896340736f
#define LN2 0.69314718055994530942f

__device__ __forceinline__ float fast_exp2(float x) { return __builtin_amdgcn_exp2f(x); }
__device__ __forceinline__ float fast_log2(float x) { return __builtin_amdgcn_logf(x); }
__device__ __forceinline__ float fast_rcp(float x) { return __builtin_amdgcn_rcpf(x); }

// arg pre-scaled by LOG2E: softplus(x), t = x*LOG2E
__device__ __forceinline__ float softplus_t(float t) {
    float sp = LN2 * fast_log2(1.0f + fast_exp2(t));
    return (t > 28.9f) ? t * LN2 : sp;
}
// arg pre-scaled by 2*LOG2E: tanh(x), t = 2x*LOG2E
__device__ __forceinline__ float tanh_t(float t) {
    float e = fast_exp2(t);
    return 1.0f - 2.0f * fast_rcp(1.0f + e);
}

// f32 -> bf16 (RNE), result in low 16 bits
__device__ __forceinline__ uint32_t cvt_bf16(float a) {
    uint32_t r;
    asm("v_cvt_pk_bf16_f32 %0, %1, %2" : "=v"(r) : "v"(a), "v"(a));
    return r;
}
__device__ __forceinline__ void store_hl(float v, uint16_t* ph, uint16_t* pl) {
    uint32_t h = cvt_bf16(v);
    float hf = __builtin_bit_cast(float, h << 16);
    uint32_t lo = cvt_bf16(v - hf);
    *ph = (uint16_t)h;
    *pl = (uint16_t)lo;
}

// lane l <-> l^16 exchange (validated in r7)
__device__ __forceinline__ float swz16(float v) {
    int r = __builtin_amdgcn_ds_swizzle(__builtin_bit_cast(int, v), 0x401F);
    return __builtin_bit_cast(float, r);
}

// B=4096, L=64, C=7, H=32, K=2 -> 504 RK4 stages, h=0.5
// Block: 512 threads (8 waves), 16 batch rows. Grid: 256 blocks. 2 barriers/stage.
// Phase A (GEMV1^T): D1[i][b] = W1p @ z^T; wave w -> tile w&1, extracts reg w>>1
//   -> 1 softplus/lane, writes h1t[b][i].
// Phase B (GEMV2^T): D2[n][b] = W2p @ h1^T, 16 tiles, wave w -> tiles {2w,2w+1};
//   in-lane c-contraction (tanh*dx FMAs over regs) + swz16 partner add;
//   duty z[b=ar][h2a], z[b=ar][h2b] per lane (dup x2 over l^16, benign).
__global__ __launch_bounds__(512, 2) void cde_kernel(
    const float* __restrict__ x,    // (4096,64,7)
    const float* __restrict__ Wi,   // (32,7)
    const float* __restrict__ bi,   // (32,)
    const float* __restrict__ W1,   // (32,32)
    const float* __restrict__ b1,   // (32,)
    const float* __restrict__ W2,   // (224,32)
    const float* __restrict__ b2,   // (224,)
    const float* __restrict__ Wo1,  // (16,32)
    const float* __restrict__ bo1,  // (16,)
    const float* __restrict__ Wo2,  // (3,16)
    const float* __restrict__ bo2,  // (3,)
    float* __restrict__ out)        // (4096,3)
{
    __shared__ float diffs[16][441];                     // [b][i*7+c]
    __shared__ alignas(16) float dxA[16][12];            // [b][c], col7=0, 48B stride
    __shared__ alignas(16) float dxB[16][12];
    __shared__ alignas(16) uint16_t zth[16][40], ztl[16][40];  // z^T-feed [b][h], 80B stride
    __shared__ alignas(16) uint16_t hth[16][40], htl[16][40];  // h1 [b][i]
    __shared__ float zfin[16][32];
    __shared__ float wo1t[32][16];
    __shared__ float ubuf[16][16];

    const int tid = threadIdx.x;
    const int l = tid & 63;
    const int w = tid >> 6;          // wave 0..7
    const int r0 = blockIdx.x * 16;

    const int ar = l & 15;           // A-row / B-col(batch) / D-col(batch)
    const int q = l >> 4;            // k-chunk & D-row quarter

    // phase-A duty
    const int T1 = w & 1;
    const int rw = w >> 1;
    const int i1 = 16 * T1 + 4 * q + rw;   // h1 index produced by this lane

    // phase-B duty (z ownership)
    const int h2a = 4 * w + (q >> 1);
    const int h2b = h2a + 2;

    // dx producer duty: wave w -> batch rows {2w, 2w+1}
    const int bdx = 2 * w + (l >> 5);
    const int cdx = l & 31;
    const bool dxact = cdx < 7;

    // ---- W1 A-frag (tile T1) + per-reg bias, pre-scaled LOG2E, hi/lo ----
    bf16x8 a1h, a1l;
    {
        const float* p = &W1[(16 * T1 + ar) * 32 + 8 * q];
#pragma unroll
        for (int j = 0; j < 8; ++j) {
            float v = p[j] * LOG2E;
            bf16_t hh = (bf16_t)v;
            a1h[j] = hh;
            a1l[j] = (bf16_t)(v - (float)hh);
        }
    }
    f32x4 b1v;
#pragma unroll
    for (int r = 0; r < 4; ++r) b1v[r] = b1[16 * T1 + 4 * q + r] * LOG2E;

    // ---- W2 A-frags tiles {2w, 2w+1} + per-reg bias, pre-scaled 2*LOG2E ----
    bf16x8 a2h[2], a2l[2];
    f32x4 b2v[2];
#pragma unroll
    for (int t = 0; t < 2; ++t) {
        const int T = 2 * w + t;
        const int hh2 = 2 * T + (ar >> 3);
        const int cc = ar & 7;
        if (cc < 7) {
            const float* p = &W2[(hh2 * 7 + cc) * 32 + 8 * q];
#pragma unroll
            for (int j = 0; j < 8; ++j) {
                float v = p[j] * (2.0f * LOG2E);
                bf16_t hv = (bf16_t)v;
                a2h[t][j] = hv;
                a2l[t][j] = (bf16_t)(v - (float)hv);
            }
        } else {
#pragma unroll
            for (int j = 0; j < 8; ++j) { a2h[t][j] = (bf16_t)0.0f; a2l[t][j] = (bf16_t)0.0f; }
        }
#pragma unroll
        for (int r = 0; r < 4; ++r) {
            int c = 4 * (q & 1) + r;
            int hq = 2 * T + (q >> 1);
            b2v[t][r] = (c < 7) ? b2[hq * 7 + c] * (2.0f * LOG2E) : 0.0f;
        }
    }

    // ---- hoisted LDS pointers ----
    const bf16x8* pZh = (const bf16x8*)&zth[ar][8 * q];
    const bf16x8* pZl = (const bf16x8*)&ztl[ar][8 * q];
    const bf16x8* pHh = (const bf16x8*)&hth[ar][8 * q];
    const bf16x8* pHl = (const bf16x8*)&htl[ar][8 * q];
    const f32x4* pDxA = (const f32x4*)&dxA[ar][4 * (q & 1)];
    const f32x4* pDxB = (const f32x4*)&dxB[ar][4 * (q & 1)];
    uint16_t* pWh = &hth[ar][i1];
    uint16_t* pWl = &htl[ar][i1];
    uint16_t* pZah = &zth[ar][h2a];
    uint16_t* pZal = &ztl[ar][h2a];
    uint16_t* pZbh = &zth[ar][h2b];
    uint16_t* pZbl = &ztl[ar][h2b];

    // ---- prologue: diffs, dx init, z0 ----
    for (int e = tid; e < 16 * 441; e += 512) {
        int r = e / 441, rem = e - r * 441;
        const float* px = &x[(size_t)(r0 + r) * 448];
        diffs[r][rem] = px[rem + 7] - px[rem];
    }
    if (tid < 16) { dxA[tid][7] = 0.0f; dxB[tid][7] = 0.0f; }
    if (dxact) {   // dxA(t=0) = diffs[b][c] (i=0, f=0), direct from x (no barrier dep)
        const float* px = &x[(size_t)(r0 + bdx) * 448];
        dxA[bdx][cdx] = px[cdx + 7] - px[cdx];
    }
    float zb0, zb1, ka0 = 0.0f, ka1 = 0.0f;
    {
        const float* px = &x[(size_t)(r0 + ar) * 448];
        float a0 = bi[h2a], a1 = bi[h2b];
#pragma unroll
        for (int c = 0; c < 7; ++c) {
            a0 += px[c] * Wi[h2a * 7 + c];
            a1 += px[c] * Wi[h2b * 7 + c];
        }
        zb0 = a0; zb1 = a1;
        store_hl(zb0, pZah, pZal);
        store_hl(zb1, pZbh, pZbl);
    }
    __syncthreads();

    const f32x4 zero4 = {0.0f, 0.0f, 0.0f, 0.0f};

    for (int k = 0; k < 126; ++k) {
#pragma unroll
        for (int s = 0; s < 4; ++s) {
            // ---------- phase A: GEMV1^T + dx producer ----------
            {
                bf16x8 bzh = *pZh;
                bf16x8 bzl = *pZl;
                f32x4 m1 = __builtin_amdgcn_mfma_f32_16x16x32_bf16(a1h, bzh, b1v, 0, 0, 0);
                f32x4 m2 = __builtin_amdgcn_mfma_f32_16x16x32_bf16(a1h, bzl, zero4, 0, 0, 0);
                f32x4 m3 = __builtin_amdgcn_mfma_f32_16x16x32_bf16(a1l, bzh, zero4, 0, 0, 0);
                float X;
                if (rw == 0)      X = m1[0] + m2[0] + m3[0];
                else if (rw == 1) X = m1[1] + m2[1] + m3[1];
                else if (rw == 2) X = m1[2] + m2[2] + m3[2];
                else              X = m1[3] + m2[3] + m3[3];
                store_hl(softplus_t(X), pWh, pWl);
            }
            if ((s == 0 || s == 1) && dxact) {   // compute one stage ahead
                int m = 2 * k + 1 + s;           // s=0: t+1/4 -> dxB ; s=1: t+1/2 -> dxA
                int i = m >> 2; if (i > 62) i = 62;
                float f = 0.25f * (float)(m - 4 * i);
                float D = diffs[bdx][i * 7 + cdx];
                float a = diffs[bdx][(i > 0 ? i - 1 : 0) * 7 + cdx];
                float val = a + (D - a) * (f * (4.0f - 3.0f * f));
                if (s == 0) dxB[bdx][cdx] = val;
                else        dxA[bdx][cdx] = val;
            }
            __syncthreads();

            // ---------- phase B: GEMV2^T + in-lane contraction + RK4 ----------
            {
                bf16x8 bhh = *pHh;
                bf16x8 bhl = *pHl;
                f32x4 dxv = (s == 0 || s == 3) ? *pDxA : *pDxB;
                float ks0, ks1;
#pragma unroll
                for (int t = 0; t < 2; ++t) {
                    f32x4 n1 = __builtin_amdgcn_mfma_f32_16x16x32_bf16(a2h[t], bhh, b2v[t], 0, 0, 0);
                    f32x4 n2 = __builtin_amdgcn_mfma_f32_16x16x32_bf16(a2h[t], bhl, zero4, 0, 0, 0);
                    f32x4 n3 = __builtin_amdgcn_mfma_f32_16x16x32_bf16(a2l[t], bhh, zero4, 0, 0, 0);
                    float pk = 0.0f;
#pragma unroll
                    for (int r = 0; r < 4; ++r)
                        pk += tanh_t(n1[r] + n2[r] + n3[r]) * dxv[r];
                    float kst = pk + swz16(pk);
                    if (t == 0) ks0 = kst; else ks1 = kst;
                }
                float zs0, zs1;
                if (s == 0) {
                    ka0 = ks0; ka1 = ks1;
                    zs0 = zb0 + 0.25f * ks0; zs1 = zb1 + 0.25f * ks1;
                } else if (s == 1) {
                    ka0 += 2.0f * ks0; ka1 += 2.0f * ks1;
                    zs0 = zb0 + 0.25f * ks0; zs1 = zb1 + 0.25f * ks1;
                } else if (s == 2) {
                    ka0 += 2.0f * ks0; ka1 += 2.0f * ks1;
                    zs0 = zb0 + 0.5f * ks0; zs1 = zb1 + 0.5f * ks1;
                } else {
                    zb0 += (1.0f / 12.0f) * (ka0 + ks0);
                    zb1 += (1.0f / 12.0f) * (ka1 + ks1);
                    zs0 = zb0; zs1 = zb1;
                }
                store_hl(zs0, pZah, pZal);
                store_hl(zs1, pZbh, pZbl);
            }
            __syncthreads();
        }
    }

    // ---- epilogue: out = softplus(z @ Wo1^T + bo1) @ Wo2^T + bo2 ----
    zfin[ar][h2a] = zb0;
    zfin[ar][h2b] = zb1;
    {
        int hh = tid >> 4, jj = tid & 15;
        wo1t[hh][jj] = Wo1[jj * 32 + hh];
    }
    __syncthreads();
    if (tid < 256) {
        int r = tid >> 4, jj = tid & 15;
        float acc = bo1[jj];
#pragma unroll
        for (int hh = 0; hh < 32; ++hh) acc += zfin[r][hh] * wo1t[hh][jj];
        ubuf[r][jj] = softplus_t(acc * LOG2E);
    }
    __syncthreads();
    if (tid < 48) {
        int r = tid / 3, o = tid - (tid / 3) * 3;
        float acc = bo2[o];
#pragma unroll
        for (int j = 0; j < 16; ++j) acc += ubuf[r][j] * Wo2[o * 16 + j];
        out[(size_t)(r0 + r) * 3 + o] = acc;
    }
}

extern "C" void kernel_launch(void* const* d_in, const int* in_sizes, int n_in,
                              void* d_out, int out_size, void* d_ws, size_t ws_size,
                              hipStream_t stream) {
    (void)in_sizes; (void)n_in; (void)d_ws; (void)ws_size; (void)out_size;
    const float* x   = (const float*)d_in[0];
    const float* Wi  = (const float*)d_in[1];
    const float* bi  = (const float*)d_in[2];
    const float* W1  = (const float*)d_in[3];
    const float* b1  = (const float*)d_in[4];
    const float* W2  = (const float*)d_in[5];
    const float* b2  = (const float*)d_in[6];
    const float* Wo1 = (const float*)d_in[7];
    const float* bo1 = (const float*)d_in[8];
    const float* Wo2 = (const float*)d_in[9];
    const float* bo2 = (const float*)d_in[10];
    cde_kernel<<<dim3(256), dim3(512), 0, stream>>>(x, Wi, bi, W1, b1, W2, b2,
                                                    Wo1, bo1, Wo2, bo2, (float*)d_out);
}